// Round 6
// baseline (189.533 us; speedup 1.0000x reference)
//
#include <hip/hip_runtime.h>

#define SC 20
#define EDIM 16
#define HDIM 10
#define NG 40          // 4*H
#define VOCAB 256
#define TROW 52        // padded ctab row stride (floats)
#define SENT VOCAB     // sentinel zero row index

#if __has_builtin(__builtin_amdgcn_exp2f)
#define EXP2F(x) __builtin_amdgcn_exp2f(x)
#else
#define EXP2F(x) exp2f(x)
#endif
#if __has_builtin(__builtin_amdgcn_rcpf)
#define RCPF(x) __builtin_amdgcn_rcpf(x)
#else
#define RCPF(x) (1.0f / (x))
#endif

#define L2E 1.44269504088896340736f

__device__ __forceinline__ float fast_sig(float x) {
    return RCPF(1.0f + EXP2F(-x * L2E));
}
__device__ __forceinline__ float fast_tanh(float x) {
    float e = EXP2F(x * (2.0f * L2E));
    return 1.0f - 2.0f * RCPF(1.0f + e);
}
__device__ __forceinline__ void add4(float4& a, const float4 b) {
    a.x += b.x; a.y += b.y; a.z += b.z; a.w += b.w;
}
// acc[0..19] += x * {w0..w4}
__device__ __forceinline__ void fma20(float* acc, float x,
    float4 w0, float4 w1, float4 w2, float4 w3, float4 w4) {
    acc[0]  += x * w0.x; acc[1]  += x * w0.y; acc[2]  += x * w0.z; acc[3]  += x * w0.w;
    acc[4]  += x * w1.x; acc[5]  += x * w1.y; acc[6]  += x * w1.z; acc[7]  += x * w1.w;
    acc[8]  += x * w2.x; acc[9]  += x * w2.y; acc[10] += x * w2.z; acc[11] += x * w2.w;
    acc[12] += x * w3.x; acc[13] += x * w3.y; acc[14] += x * w3.z; acc[15] += x * w3.w;
    acc[16] += x * w4.x; acc[17] += x * w4.y; acc[18] += x * w4.z; acc[19] += x * w4.w;
}

// conv gather for one sequence into xv[0..11]
__device__ __forceinline__ void conv_gather(const float* ctab, int a0, int a1,
                                            int a2, int a3, float* xv) {
    const float4* r0 = (const float4*)(ctab + a0 * TROW);
    const float4* r1 = (const float4*)(ctab + a1 * TROW + 12);
    const float4* r2 = (const float4*)(ctab + a2 * TROW + 24);
    const float4* r3 = (const float4*)(ctab + a3 * TROW + 36);
    float4 C0 = r0[0], C1 = r0[1], C2 = r0[2];
    add4(C0, r1[0]); add4(C1, r1[1]); add4(C2, r1[2]);
    add4(C0, r2[0]); add4(C1, r2[1]); add4(C2, r2[2]);
    /* age-3 f0..3 block is all zeros -> skip */
    add4(C1, r3[1]); add4(C2, r3[2]);
    xv[0] = C0.x; xv[1] = C0.y; xv[2]  = C0.z; xv[3]  = C0.w;
    xv[4] = C1.x; xv[5] = C1.y; xv[6]  = C1.z; xv[7]  = C1.w;
    xv[8] = C2.x; xv[9] = C2.y; xv[10] = C2.z; xv[11] = C2.w;
}

// one GEMV pass over 20 gate columns starting at float col `cof*4`:
// za_A/za_B = bias + [xvA/xvB] @ W[:, cof*4 .. cof*4+19]
// W rows are read once from GLOBAL (L1-broadcast) and feed both sequences.
#define GEMV_PASS(zaA, zaB, cof)                                              \
    {                                                                         \
        const float4* bg = (const float4*)Bv + (cof);                         \
        float4 b0 = bg[0], b1 = bg[1], b2 = bg[2], b3 = bg[3], b4 = bg[4];    \
        zaA[0]=b0.x; zaA[1]=b0.y; zaA[2]=b0.z; zaA[3]=b0.w;                   \
        zaA[4]=b1.x; zaA[5]=b1.y; zaA[6]=b1.z; zaA[7]=b1.w;                   \
        zaA[8]=b2.x; zaA[9]=b2.y; zaA[10]=b2.z; zaA[11]=b2.w;                 \
        zaA[12]=b3.x; zaA[13]=b3.y; zaA[14]=b3.z; zaA[15]=b3.w;               \
        zaA[16]=b4.x; zaA[17]=b4.y; zaA[18]=b4.z; zaA[19]=b4.w;               \
        _Pragma("unroll")                                                     \
        for (int j = 0; j < 20; ++j) zaB[j] = zaA[j];                         \
        float4 u0 = wg[(cof)], u1 = wg[(cof)+1], u2 = wg[(cof)+2],            \
               u3 = wg[(cof)+3], u4 = wg[(cof)+4];                            \
        float4 v0, v1, v2, v3, v4;                                            \
        _Pragma("unroll")                                                     \
        for (int dd = 0; dd < 11; ++dd) {                                     \
            const int d0 = 2 * dd, d1 = 2 * dd + 1;                           \
            v0 = wg[d1*10+(cof)];   v1 = wg[d1*10+(cof)+1];                   \
            v2 = wg[d1*10+(cof)+2]; v3 = wg[d1*10+(cof)+3];                   \
            v4 = wg[d1*10+(cof)+4];                                           \
            fma20(zaA, xvA[d0], u0, u1, u2, u3, u4);                          \
            fma20(zaB, xvB[d0], u0, u1, u2, u3, u4);                          \
            __builtin_amdgcn_sched_barrier(0);                                \
            if (dd < 10) {                                                    \
                u0 = wg[(d0+2)*10+(cof)];   u1 = wg[(d0+2)*10+(cof)+1];       \
                u2 = wg[(d0+2)*10+(cof)+2]; u3 = wg[(d0+2)*10+(cof)+3];       \
                u4 = wg[(d0+2)*10+(cof)+4];                                   \
            }                                                                 \
            fma20(zaA, xvA[d1], v0, v1, v2, v3, v4);                          \
            fma20(zaB, xvB[d1], v0, v1, v2, v3, v4);                          \
            __builtin_amdgcn_sched_barrier(0);                                \
        }                                                                     \
    }

__global__ __launch_bounds__(256, 1) void cnn_lstm_kernel(
    const int* __restrict__ inp, const float* __restrict__ emb,
    const float* __restrict__ k2, const float* __restrict__ k3,
    const float* __restrict__ k4,
    const float* __restrict__ wfw, const float* __restrict__ bfw,
    const float* __restrict__ wbw, const float* __restrict__ bbw,
    float* __restrict__ out)
{
    // ctab[v][age][f]: contribution of char v seen `age` steps ago to the 12
    // conv outputs at the current position. Row SENT is all zeros.
    __shared__ float ctab[(VOCAB + 1) * TROW];

    const int tid = threadIdx.x;

    // ---- build ctab: thread v = tid handles one vocab row ------------------
    {
        float er[EDIM];
        const float4* ep = (const float4*)(emb + tid * EDIM);
        float4 e0 = ep[0], e1 = ep[1], e2 = ep[2], e3 = ep[3];
        er[0] = e0.x; er[1] = e0.y; er[2] = e0.z; er[3] = e0.w;
        er[4] = e1.x; er[5] = e1.y; er[6] = e1.z; er[7] = e1.w;
        er[8] = e2.x; er[9] = e2.y; er[10] = e2.z; er[11] = e2.w;
        er[12] = e3.x; er[13] = e3.y; er[14] = e3.z; er[15] = e3.w;

        float* dst = ctab + tid * TROW;
        #pragma unroll
        for (int dlt = 0; dlt < 4; ++dlt) {
            float o[12];
            #pragma unroll
            for (int f = 0; f < 12; ++f) o[f] = 0.0f;
            const int tap2 = 1 - dlt, tap3 = 2 - dlt, tap4 = 3 - dlt;
            if (tap2 >= 0) {
                #pragma unroll
                for (int e = 0; e < EDIM; ++e) {
                    const float x = er[e];
                    #pragma unroll
                    for (int f = 0; f < 3; ++f) o[f] += x * k2[(tap2 * EDIM + e) * 3 + f];
                }
            }
            if (tap3 >= 0) {
                #pragma unroll
                for (int e = 0; e < EDIM; ++e) {
                    const float x = er[e];
                    #pragma unroll
                    for (int f = 0; f < 4; ++f) o[3 + f] += x * k3[(tap3 * EDIM + e) * 4 + f];
                }
            }
            {
                #pragma unroll
                for (int e = 0; e < EDIM; ++e) {
                    const float x = er[e];
                    #pragma unroll
                    for (int f = 0; f < 5; ++f) o[7 + f] += x * k4[(tap4 * EDIM + e) * 5 + f];
                }
            }
            #pragma unroll
            for (int f = 0; f < 12; ++f) dst[dlt * 12 + f] = o[f];
        }
    }
    if (tid < TROW) ctab[VOCAB * TROW + tid] = 0.0f;  // sentinel zero row
    __syncthreads();

    // ---- two sequences per thread, same direction ---------------------------
    const int dir = blockIdx.x >> 7;              // blocks 0..127 fw, 128..255 bw
    const bool fw = (dir == 0);
    const int nA = (blockIdx.x & 127) * 256 + tid;      // 0..32767
    const int nB = nA + 32768;                          // 32768..65535
    const int* inpA = inp + nA * SC;
    const int* inpB = inp + nB * SC;
    const float4* wg = (const float4*)(fw ? wfw : wbw); // W in GLOBAL (L1 broadcast)
    const float*  Bv = fw ? bfw : bbw;

    // xv = [conv feats (12), h (10)] per sequence
    float xvA[22], xvB[22], csA[HDIM], csB[HDIM];
    #pragma unroll
    for (int q = 0; q < HDIM; ++q) {
        xvA[12 + q] = 0.0f; xvB[12 + q] = 0.0f;
        csA[q] = 0.0f;      csB[q] = 0.0f;
    }

    int aA0, aA1, aA2, aA3, aB0, aB1, aB2, aB3;
    if (fw) {
        aA0 = inpA[0]; aA1 = SENT; aA2 = SENT; aA3 = SENT;
        aB0 = inpB[0]; aB1 = SENT; aB2 = SENT; aB3 = SENT;
    } else {
        aA0 = inpA[SC-1]; aA1 = inpA[SC-2]; aA2 = inpA[SC-3]; aA3 = inpA[SC-4];
        aB0 = inpB[SC-1]; aB1 = inpB[SC-2]; aB2 = inpB[SC-3]; aB3 = inpB[SC-4];
    }

    #pragma unroll 1
    for (int t = 0; t < SC; ++t) {
        // prefetch next char indices (consumed at bottom)
        const int nidx = fw ? (t + 1) : (SC - 5 - t);
        int anA = SENT, anB = SENT;
        if ((t < SC - 1) && (nidx >= 0)) { anA = inpA[nidx]; anB = inpB[nidx]; }

        // ---- conv gathers (LDS) --------------------------------------------
        conv_gather(ctab, aA0, aA1, aA2, aA3, xvA);
        conv_gather(ctab, aB0, aB1, aB2, aB3, xvB);
        __builtin_amdgcn_sched_barrier(0);

        // ---- pass 1: gate cols 0..19 (i, j) ---------------------------------
        float zaA[20], zaB[20];
        GEMV_PASS(zaA, zaB, 0)
        float ijA[HDIM], ijB[HDIM];
        #pragma unroll
        for (int q = 0; q < HDIM; ++q) {
            ijA[q] = fast_sig(zaA[q]) * fast_tanh(zaA[HDIM + q]);
            ijB[q] = fast_sig(zaB[q]) * fast_tanh(zaB[HDIM + q]);
        }

        // ---- pass 2: gate cols 20..39 (f, o) --------------------------------
        float zbA[20], zbB[20];
        GEMV_PASS(zbA, zbB, 5)
        #pragma unroll
        for (int q = 0; q < HDIM; ++q) {
            const float fgA = fast_sig(zbA[q] + 1.0f);
            const float ogA = fast_sig(zbA[HDIM + q]);
            csA[q] = fgA * csA[q] + ijA[q];
            xvA[12 + q] = ogA * fast_tanh(csA[q]);
            const float fgB = fast_sig(zbB[q] + 1.0f);
            const float ogB = fast_sig(zbB[HDIM + q]);
            csB[q] = fgB * csB[q] + ijB[q];
            xvB[12 + q] = ogB * fast_tanh(csB[q]);
        }

        // ---- advance rolling char windows -----------------------------------
        if (fw) {
            aA3 = aA2; aA2 = aA1; aA1 = aA0; aA0 = anA;
            aB3 = aB2; aB2 = aB1; aB1 = aB0; aB0 = anB;
        } else {
            aA0 = aA1; aA1 = aA2; aA2 = aA3; aA3 = anA;
            aB0 = aB1; aB1 = aB2; aB2 = aB3; aB3 = anB;
        }
    }

    #pragma unroll
    for (int q = 0; q < HDIM; ++q) {
        out[nA * (2 * HDIM) + dir * HDIM + q] = xvA[12 + q];
        out[nB * (2 * HDIM) + dir * HDIM + q] = xvB[12 + q];
    }
}

extern "C" void kernel_launch(void* const* d_in, const int* in_sizes, int n_in,
                              void* d_out, int out_size, void* d_ws, size_t ws_size,
                              hipStream_t stream) {
    const int*   inp = (const int*)d_in[0];
    const float* emb = (const float*)d_in[1];
    const float* k2  = (const float*)d_in[2];
    const float* k3  = (const float*)d_in[3];
    const float* k4  = (const float*)d_in[4];
    const float* wfw = (const float*)d_in[5];
    const float* bfw = (const float*)d_in[6];
    const float* wbw = (const float*)d_in[7];
    const float* bbw = (const float*)d_in[8];
    float* out = (float*)d_out;

    cnn_lstm_kernel<<<dim3(256), dim3(256), 0, stream>>>(
        inp, emb, k2, k3, k4, wfw, bfw, wbw, bbw, out);
}